// Round 2
// baseline (298.079 us; speedup 1.0000x reference)
//
#include <hip/hip_runtime.h>
#include <hip/hip_bf16.h>

// Problem constants
#define N_ATOMS 262144
#define B_SZ    64
#define H_DIM   256
#define R_DIM   512

typedef __attribute__((ext_vector_type(8))) short bf16x8;
typedef __attribute__((ext_vector_type(4))) short bf16x4;
typedef __attribute__((ext_vector_type(4))) float f32x4;

static __device__ __forceinline__ short f2bf(float f) {
  unsigned u = __builtin_bit_cast(unsigned, f);
  u = (u + 0x7FFFu + ((u >> 16) & 1u)) >> 16;   // RNE
  return (short)u;
}

// ---------------------------------------------------------------------------
// Prep kernel (fused):
//   blocks [0,64):  pooled[b][o] = bl[o] + retj . Wl[o,256:512]
//                   retj[j]      = bp[j] + meanr . Wp[j,:]
//                   meanr[r]     = mean_k ret_feat[b][k][r]
//     (wave-per-16-outputs, lane-parallel dots, shfl_xor reduce)
//   blocks [64,80): convert Wl[:, :256] to bf16 in MFMA B-fragment order:
//     Bbf[((ct*8+ks)*64+lane)*8+j] = Wl[ct*16+(lane&15)][ks*32+(lane>>4)*8+j]
// ---------------------------------------------------------------------------
__global__ __launch_bounds__(1024) void prep_kernel(
    const float* __restrict__ rf, const float* __restrict__ Wp,
    const float* __restrict__ bp, const float* __restrict__ Wl,
    const float* __restrict__ bl, float* __restrict__ pooled,
    short* __restrict__ Bbf) {
  int t = threadIdx.x;
  if (blockIdx.x >= B_SZ) {
    int base = (blockIdx.x - B_SZ) * 4096 + t * 4;
#pragma unroll
    for (int q = 0; q < 4; ++q) {
      int idx  = base + q;
      int j    = idx & 7;
      int lane = (idx >> 3) & 63;
      int ks   = (idx >> 9) & 7;
      int ct   = idx >> 12;
      int o    = ct * 16 + (lane & 15);
      int k    = ks * 32 + ((lane >> 4) << 3) + j;
      Bbf[idx] = f2bf(Wl[o * (2 * H_DIM) + k]);
    }
    return;
  }

  __shared__ float meanr[R_DIM];
  __shared__ float retj[H_DIM];
  int b    = blockIdx.x;
  int lane = t & 63;
  int w    = t >> 6;            // 16 waves

  // phase 1: mean over K=16  (threads 0..511)
  if (t < R_DIM) {
    float s = 0.f;
    const float* p = rf + (long)b * 16 * R_DIM + t;
#pragma unroll
    for (int k = 0; k < 16; ++k) s += p[k * R_DIM];
    meanr[t] = s * (1.f / 16.f);
  }
  __syncthreads();

  // phase 2: retj[j] = bp[j] + meanr . Wp[j,:]   (wave w owns j = 16w..16w+15)
  {
    f32x4 m0 = *(const f32x4*)&meanr[lane * 8];
    f32x4 m1 = *(const f32x4*)&meanr[lane * 8 + 4];
#pragma unroll
    for (int jj = 0; jj < 16; ++jj) {
      int j = w * 16 + jj;
      const f32x4* wp = (const f32x4*)(Wp + (long)j * R_DIM + lane * 8);
      f32x4 w0 = wp[0], w1 = wp[1];
      float s = m0[0]*w0[0] + m0[1]*w0[1] + m0[2]*w0[2] + m0[3]*w0[3]
              + m1[0]*w1[0] + m1[1]*w1[1] + m1[2]*w1[2] + m1[3]*w1[3];
#pragma unroll
      for (int d = 1; d < 64; d <<= 1) s += __shfl_xor(s, d);
      if (lane == 0) retj[j] = s + bp[j];
    }
  }
  __syncthreads();

  // phase 3: pooled[b][o] = bl[o] + retj . Wl[o,256:512]
  {
    f32x4 r0 = *(const f32x4*)&retj[lane * 4];
#pragma unroll
    for (int oo = 0; oo < 16; ++oo) {
      int o = w * 16 + oo;
      f32x4 wv = *(const f32x4*)(Wl + (long)o * (2 * H_DIM) + H_DIM + lane * 4);
      float s = r0[0]*wv[0] + r0[1]*wv[1] + r0[2]*wv[2] + r0[3]*wv[3];
#pragma unroll
      for (int d = 1; d < 64; d <<= 1) s += __shfl_xor(s, d);
      if (lane == 0) pooled[b * H_DIM + o] = s + bl[o];
    }
  }
}

// ---------------------------------------------------------------------------
// GEMM: out[n][o] = sum_k h[n][k]*Wl[o][k] + pooled[batch[n]][o]
// 256 threads = 4 waves per block; block owns 64 rows x 256 cols.
// Wave w loops over 4 col-tiles (ct = 4w..4w+3); B strip (8 x bf16x8) reloaded
// from L2-resident Bbf per tile; A staged once in LDS (bf16, XOR-swizzled).
// ---------------------------------------------------------------------------
__global__ __launch_bounds__(256, 4) void gemm_kernel(
    const float* __restrict__ h, const short* __restrict__ Bbf,
    const float* __restrict__ pooled, const int* __restrict__ batch,
    float* __restrict__ out) {
  __shared__ short As[64 * 256];   // 32 KiB bf16, swizzled
  int t    = threadIdx.x;
  int lane = t & 63;
  int w    = t >> 6;
  long m0  = (long)blockIdx.x * 64;

  // --- stage A tile: 64 rows x 256 cols f32 -> bf16 LDS, 1KB/wave-instr ---
  {
    const f32x4* src = (const f32x4*)(h + m0 * H_DIM);
#pragma unroll
    for (int i = 0; i < 16; ++i) {
      int vi = i * 256 + t;             // f32x4 index in tile
      f32x4 v = src[vi];
      bf16x4 bv;
      bv[0] = f2bf(v[0]); bv[1] = f2bf(v[1]);
      bv[2] = f2bf(v[2]); bv[3] = f2bf(v[3]);
      int e   = vi << 2;
      int row = e >> 8;
      int col = e & 255;
      int off = (row << 9) + (col << 1);
      *(bf16x4*)((char*)As + (off ^ ((row & 7) << 4))) = bv;
    }
  }
  __syncthreads();

  int arow  = lane & 15;
  int kbyte = (lane >> 4) << 4;
  int ocol  = lane & 15;

#pragma unroll
  for (int ci = 0; ci < 4; ++ci) {
    int ct = w * 4 + ci;
    bf16x8 bfrag[8];
#pragma unroll
    for (int ks = 0; ks < 8; ++ks)
      bfrag[ks] = *(const bf16x8*)(Bbf + (((ct * 8 + ks) * 64 + lane) << 3));
#pragma unroll
    for (int rt = 0; rt < 4; ++rt) {
      f32x4 acc = {0.f, 0.f, 0.f, 0.f};
      int row = rt * 16 + arow;
      int swz = (row & 7) << 4;
#pragma unroll
      for (int ks = 0; ks < 8; ++ks) {
        int off = ((row << 9) + (ks << 6) + kbyte) ^ swz;
        bf16x8 afrag = *(const bf16x8*)((const char*)As + off);
        acc = __builtin_amdgcn_mfma_f32_16x16x32_bf16(afrag, bfrag[ks], acc, 0, 0, 0);
      }
      long rbase = m0 + rt * 16 + ((lane >> 4) << 2);
      int  o     = ct * 16 + ocol;
#pragma unroll
      for (int r = 0; r < 4; ++r) {
        long rowg = rbase + r;
        int  b    = batch[rowg];
        out[rowg * H_DIM + o] = acc[r] + pooled[b * H_DIM + o];
      }
    }
  }
}

// ---------------------------------------------------------------------------
extern "C" void kernel_launch(void* const* d_in, const int* in_sizes, int n_in,
                              void* d_out, int out_size, void* d_ws, size_t ws_size,
                              hipStream_t stream) {
  const float* h   = (const float*)d_in[0];
  const float* rf  = (const float*)d_in[1];
  const int*   bat = (const int*)d_in[2];
  const float* Wp  = (const float*)d_in[3];
  const float* bp  = (const float*)d_in[4];
  const float* Wl  = (const float*)d_in[5];
  const float* bl  = (const float*)d_in[6];
  float* out = (float*)d_out;

  float* pooled = (float*)d_ws;                          // 64 KiB
  short* Bbf    = (short*)((char*)d_ws + 64 * 1024);     // 128 KiB

  prep_kernel<<<B_SZ + 16, 1024, 0, stream>>>(rf, Wp, bp, Wl, bl, pooled, Bbf);
  gemm_kernel<<<N_ATOMS / 64, 256, 0, stream>>>(h, Bbf, pooled, bat, out);
}

// Round 3
// 197.878 us; speedup vs baseline: 1.5064x; 1.5064x over previous
//
#include <hip/hip_runtime.h>
#include <hip/hip_bf16.h>

// Problem constants
#define N_ATOMS 262144
#define B_SZ    64
#define H_DIM   256
#define R_DIM   512

typedef __attribute__((ext_vector_type(8))) short bf16x8;
typedef __attribute__((ext_vector_type(4))) float f32x4;

static __device__ __forceinline__ short f2bf(float f) {
  unsigned u = __builtin_bit_cast(unsigned, f);
  u = (u + 0x7FFFu + ((u >> 16) & 1u)) >> 16;   // RNE
  return (short)u;
}

// ---------------------------------------------------------------------------
// Prep kernel (fused):
//   blocks [0,64):  pooled[b][o] = bl[o] + retj . Wl[o,256:512]
//                   retj[j]      = bp[j] + meanr . Wp[j,:]
//                   meanr[r]     = mean_k ret_feat[b][k][r]
//   blocks [64,80): convert Wl[:, :256] to bf16 in MFMA B-fragment order:
//     Bbf[((ct*8+ks)*64+lane)*8+j] = Wl[ct*16+(lane&15)][ks*32+(lane>>4)*8+j]
// ---------------------------------------------------------------------------
__global__ __launch_bounds__(1024) void prep_kernel(
    const float* __restrict__ rf, const float* __restrict__ Wp,
    const float* __restrict__ bp, const float* __restrict__ Wl,
    const float* __restrict__ bl, float* __restrict__ pooled,
    short* __restrict__ Bbf) {
  int t = threadIdx.x;
  if (blockIdx.x >= B_SZ) {
    int base = (blockIdx.x - B_SZ) * 4096 + t * 4;
#pragma unroll
    for (int q = 0; q < 4; ++q) {
      int idx  = base + q;
      int j    = idx & 7;
      int lane = (idx >> 3) & 63;
      int ks   = (idx >> 9) & 7;
      int ct   = idx >> 12;
      int o    = ct * 16 + (lane & 15);
      int k    = ks * 32 + ((lane >> 4) << 3) + j;
      Bbf[idx] = f2bf(Wl[o * (2 * H_DIM) + k]);
    }
    return;
  }

  __shared__ float meanr[R_DIM];
  __shared__ float retj[H_DIM];
  int b    = blockIdx.x;
  int lane = t & 63;
  int w    = t >> 6;            // 16 waves

  // phase 1: mean over K=16  (threads 0..511)
  if (t < R_DIM) {
    float s = 0.f;
    const float* p = rf + (long)b * 16 * R_DIM + t;
#pragma unroll
    for (int k = 0; k < 16; ++k) s += p[k * R_DIM];
    meanr[t] = s * (1.f / 16.f);
  }
  __syncthreads();

  // phase 2: retj[j] = bp[j] + meanr . Wp[j,:]   (wave w owns j = 16w..16w+15)
  {
    f32x4 m0 = *(const f32x4*)&meanr[lane * 8];
    f32x4 m1 = *(const f32x4*)&meanr[lane * 8 + 4];
#pragma unroll
    for (int jj = 0; jj < 16; ++jj) {
      int j = w * 16 + jj;
      const f32x4* wp = (const f32x4*)(Wp + (long)j * R_DIM + lane * 8);
      f32x4 w0 = wp[0], w1 = wp[1];
      float s = m0[0]*w0[0] + m0[1]*w0[1] + m0[2]*w0[2] + m0[3]*w0[3]
              + m1[0]*w1[0] + m1[1]*w1[1] + m1[2]*w1[2] + m1[3]*w1[3];
#pragma unroll
      for (int d = 1; d < 64; d <<= 1) s += __shfl_xor(s, d);
      if (lane == 0) retj[j] = s + bp[j];
    }
  }
  __syncthreads();

  // phase 3: pooled[b][o] = bl[o] + retj . Wl[o,256:512]
  {
    f32x4 r0 = *(const f32x4*)&retj[lane * 4];
#pragma unroll
    for (int oo = 0; oo < 16; ++oo) {
      int o = w * 16 + oo;
      f32x4 wv = *(const f32x4*)(Wl + (long)o * (2 * H_DIM) + H_DIM + lane * 4);
      float s = r0[0]*wv[0] + r0[1]*wv[1] + r0[2]*wv[2] + r0[3]*wv[3];
#pragma unroll
      for (int d = 1; d < 64; d <<= 1) s += __shfl_xor(s, d);
      if (lane == 0) pooled[b * H_DIM + o] = s + bl[o];
    }
  }
}

// ---------------------------------------------------------------------------
// GEMM: out[n][o] = sum_k h[n][k]*Wl[o][k] + pooled[batch[n]][o]
// NO LDS, NO BARRIERS. Each wave owns 16 rows:
//  - A-fragments (8 k-steps) loaded straight from global h in MFMA layout
//    (m = lane&15, k = (lane>>4)*8+j): per k-step the wave's two dwordx4
//    loads consume exactly 16 full 128B lines. Converted f32->bf16 in regs.
//  - Loops 16 col-tiles; B-fragments reloaded from L1/L2-hot Bbf (128 KB).
//  - Epilogue adds pooled[batch[row]][o], stores f32.
// ---------------------------------------------------------------------------
__global__ __launch_bounds__(256) void gemm_kernel(
    const float* __restrict__ h, const short* __restrict__ Bbf,
    const float* __restrict__ pooled, const int* __restrict__ batch,
    float* __restrict__ out) {
  int t    = threadIdx.x;
  int lane = t & 63;
  int w    = t >> 6;
  long m0  = (long)blockIdx.x * 64 + w * 16;
  int arow = lane & 15;
  int kgrp = lane >> 4;

  // --- A fragments: 16 rows x 256 k, f32 -> bf16, MFMA layout ---
  const float* ap = h + (m0 + arow) * H_DIM + kgrp * 8;
  bf16x8 afrag[8];
#pragma unroll
  for (int ks = 0; ks < 8; ++ks) {
    f32x4 a0 = *(const f32x4*)(ap + ks * 32);
    f32x4 a1 = *(const f32x4*)(ap + ks * 32 + 4);
    bf16x8 v;
    v[0] = f2bf(a0[0]); v[1] = f2bf(a0[1]); v[2] = f2bf(a0[2]); v[3] = f2bf(a0[3]);
    v[4] = f2bf(a1[0]); v[5] = f2bf(a1[1]); v[6] = f2bf(a1[2]); v[7] = f2bf(a1[3]);
    afrag[ks] = v;
  }

  // --- per-lane-group row info for the epilogue ---
  long rbase = m0 + (kgrp << 2);
  int b0 = batch[rbase + 0];
  int b1 = batch[rbase + 1];
  int b2 = batch[rbase + 2];
  int b3 = batch[rbase + 3];

  // --- 16 column tiles ---
#pragma unroll 2
  for (int ct = 0; ct < 16; ++ct) {
    const short* bbase = Bbf + (((long)ct * 8 * 64 + lane) << 3);
    f32x4 acc = {0.f, 0.f, 0.f, 0.f};
#pragma unroll
    for (int ks = 0; ks < 8; ++ks) {
      bf16x8 bfrag = *(const bf16x8*)(bbase + (ks << 9));
      acc = __builtin_amdgcn_mfma_f32_16x16x32_bf16(afrag[ks], bfrag, acc, 0, 0, 0);
    }
    int o = ct * 16 + arow;
    float* orow = out + rbase * H_DIM + o;
    const float* po = pooled + o;
    orow[0 * H_DIM] = acc[0] + po[b0 * H_DIM];
    orow[1 * H_DIM] = acc[1] + po[b1 * H_DIM];
    orow[2 * H_DIM] = acc[2] + po[b2 * H_DIM];
    orow[3 * H_DIM] = acc[3] + po[b3 * H_DIM];
  }
}

// ---------------------------------------------------------------------------
extern "C" void kernel_launch(void* const* d_in, const int* in_sizes, int n_in,
                              void* d_out, int out_size, void* d_ws, size_t ws_size,
                              hipStream_t stream) {
  const float* h   = (const float*)d_in[0];
  const float* rf  = (const float*)d_in[1];
  const int*   bat = (const int*)d_in[2];
  const float* Wp  = (const float*)d_in[3];
  const float* bp  = (const float*)d_in[4];
  const float* Wl  = (const float*)d_in[5];
  const float* bl  = (const float*)d_in[6];
  float* out = (float*)d_out;

  float* pooled = (float*)d_ws;                          // 64 KiB
  short* Bbf    = (short*)((char*)d_ws + 64 * 1024);     // 128 KiB

  prep_kernel<<<B_SZ + 16, 1024, 0, stream>>>(rf, Wp, bp, Wl, bl, pooled, Bbf);
  gemm_kernel<<<N_ATOMS / 64, 256, 0, stream>>>(h, Bbf, pooled, bat, out);
}

// Round 4
// 167.869 us; speedup vs baseline: 1.7757x; 1.1788x over previous
//
#include <hip/hip_runtime.h>
#include <hip/hip_bf16.h>

// Problem constants
#define N_ATOMS 262144
#define B_SZ    64
#define H_DIM   256
#define R_DIM   512

#define TILE_ROWS 32
#define N_TILES   (N_ATOMS / TILE_ROWS)   // 8192
#define TPB_TILES 8
#define NBLOCKS   (N_TILES / TPB_TILES)   // 1024

typedef __attribute__((ext_vector_type(8))) short bf16x8;
typedef __attribute__((ext_vector_type(4))) float f32x4;

static __device__ __forceinline__ short f2bf(float f) {
  unsigned u = __builtin_bit_cast(unsigned, f);
  u = (u + 0x7FFFu + ((u >> 16) & 1u)) >> 16;   // RNE
  return (short)u;
}

static __device__ __forceinline__ bf16x8 pack8(f32x4 a0, f32x4 a1) {
  bf16x8 v;
  v[0] = f2bf(a0[0]); v[1] = f2bf(a0[1]); v[2] = f2bf(a0[2]); v[3] = f2bf(a0[3]);
  v[4] = f2bf(a1[0]); v[5] = f2bf(a1[1]); v[6] = f2bf(a1[2]); v[7] = f2bf(a1[3]);
  return v;
}

// ---------------------------------------------------------------------------
// Prep kernel (fused):
//   blocks [0,64):  pooled[b][o] = bl[o] + retj . Wl[o,256:512]
//   blocks [64,80): convert Wl[:, :256] to bf16 in MFMA B-fragment order:
//     Bbf[((ct*8+ks)*64+lane)*8+j] = Wl[ct*16+(lane&15)][ks*32+(lane>>4)*8+j]
// ---------------------------------------------------------------------------
__global__ __launch_bounds__(1024) void prep_kernel(
    const float* __restrict__ rf, const float* __restrict__ Wp,
    const float* __restrict__ bp, const float* __restrict__ Wl,
    const float* __restrict__ bl, float* __restrict__ pooled,
    short* __restrict__ Bbf) {
  int t = threadIdx.x;
  if (blockIdx.x >= B_SZ) {
    int base = (blockIdx.x - B_SZ) * 4096 + t * 4;
#pragma unroll
    for (int q = 0; q < 4; ++q) {
      int idx  = base + q;
      int j    = idx & 7;
      int lane = (idx >> 3) & 63;
      int ks   = (idx >> 9) & 7;
      int ct   = idx >> 12;
      int o    = ct * 16 + (lane & 15);
      int k    = ks * 32 + ((lane >> 4) << 3) + j;
      Bbf[idx] = f2bf(Wl[o * (2 * H_DIM) + k]);
    }
    return;
  }

  __shared__ float meanr[R_DIM];
  __shared__ float retj[H_DIM];
  int b    = blockIdx.x;
  int lane = t & 63;
  int w    = t >> 6;            // 16 waves

  if (t < R_DIM) {
    float s = 0.f;
    const float* p = rf + (long)b * 16 * R_DIM + t;
#pragma unroll
    for (int k = 0; k < 16; ++k) s += p[k * R_DIM];
    meanr[t] = s * (1.f / 16.f);
  }
  __syncthreads();

  {
    f32x4 m0 = *(const f32x4*)&meanr[lane * 8];
    f32x4 m1 = *(const f32x4*)&meanr[lane * 8 + 4];
#pragma unroll
    for (int jj = 0; jj < 16; ++jj) {
      int j = w * 16 + jj;
      const f32x4* wp = (const f32x4*)(Wp + (long)j * R_DIM + lane * 8);
      f32x4 w0 = wp[0], w1 = wp[1];
      float s = m0[0]*w0[0] + m0[1]*w0[1] + m0[2]*w0[2] + m0[3]*w0[3]
              + m1[0]*w1[0] + m1[1]*w1[1] + m1[2]*w1[2] + m1[3]*w1[3];
#pragma unroll
      for (int d = 1; d < 64; d <<= 1) s += __shfl_xor(s, d);
      if (lane == 0) retj[j] = s + bp[j];
    }
  }
  __syncthreads();

  {
    f32x4 r0 = *(const f32x4*)&retj[lane * 4];
#pragma unroll
    for (int oo = 0; oo < 16; ++oo) {
      int o = w * 16 + oo;
      f32x4 wv = *(const f32x4*)(Wl + (long)o * (2 * H_DIM) + H_DIM + lane * 4);
      float s = r0[0]*wv[0] + r0[1]*wv[1] + r0[2]*wv[2] + r0[3]*wv[3];
#pragma unroll
      for (int d = 1; d < 64; d <<= 1) s += __shfl_xor(s, d);
      if (lane == 0) pooled[b * H_DIM + o] = s + bl[o];
    }
  }
}

// ---------------------------------------------------------------------------
// GEMM: out[n][o] = sum_k h[n][k]*Wl[o][k] + pooled[batch[n]][o]
// 512 threads = 8 waves. Wave w owns col-tiles {w, w+8}; B fragments for both
// held in registers (loaded once). Block grid-strides over 8 tiles of 32 rows;
// A staged in LDS in MFMA fragment-stripe order (fully linear ds_write_b128 /
// ds_read_b128 — conflict-free by construction), double-buffered, with
// T14-style async staging: issue next tile's global loads before compute,
// ds_write after compute, one barrier per tile.
// LDS stripe S = rt*8+ks holds afrag bytes: As[buf][S*64+lane] = 16B frag.
// ---------------------------------------------------------------------------
__global__ __launch_bounds__(512) void gemm_kernel(
    const float* __restrict__ h, const short* __restrict__ Bbf,
    const float* __restrict__ pooled, const int* __restrict__ batch,
    float* __restrict__ out) {
  __shared__ short As[2][16 * 64 * 8];    // 2 x 16 KiB
  int t    = threadIdx.x;
  int lane = t & 63;
  int w    = t >> 6;                       // 0..7

  // --- B fragments for col-tiles w and w+8, loaded once (64 VGPR) ---
  bf16x8 bfrag0[8], bfrag1[8];
#pragma unroll
  for (int ks = 0; ks < 8; ++ks) {
    bfrag0[ks] = *(const bf16x8*)(Bbf + (((w * 8 + ks) * 64 + lane) << 3));
    bfrag1[ks] = *(const bf16x8*)(Bbf + ((((w + 8) * 8 + ks) * 64 + lane) << 3));
  }

  // staging geometry: wave w stages stripes S0=2w, S1=2w+1
  int S0 = 2 * w, S1 = 2 * w + 1;
  int r_in0 = ((S0 >> 3) << 4) + (lane & 15);          // row within tile
  int r_in1 = ((S1 >> 3) << 4) + (lane & 15);
  int kf0   = ((S0 & 7) << 5) + ((lane >> 4) << 3);    // k-float offset
  int kf1   = ((S1 & 7) << 5) + ((lane >> 4) << 3);
  int ldso0 = (S0 * 64 + lane) << 3;                   // short index in As
  int ldso1 = (S1 * 64 + lane) << 3;

  long tile0 = (long)blockIdx.x * TPB_TILES;

  // --- prologue: stage tile0 into buf 0 ---
  {
    const float* p0 = h + (tile0 * TILE_ROWS + r_in0) * H_DIM + kf0;
    const float* p1 = h + (tile0 * TILE_ROWS + r_in1) * H_DIM + kf1;
    f32x4 a0 = *(const f32x4*)p0, a1 = *(const f32x4*)(p0 + 4);
    f32x4 c0 = *(const f32x4*)p1, c1 = *(const f32x4*)(p1 + 4);
    *(bf16x8*)&As[0][ldso0] = pack8(a0, a1);
    *(bf16x8*)&As[0][ldso1] = pack8(c0, c1);
  }
  __syncthreads();

  int o0 = (w << 4) + (lane & 15);
  int o1 = ((w + 8) << 4) + (lane & 15);

  for (int tt = 0; tt < TPB_TILES; ++tt) {
    int buf = tt & 1;
    long g  = tile0 + tt;

    // --- issue next tile's global loads (latency hides under MFMA) ---
    f32x4 n0, n1, n2, n3;
    bool have_next = (tt + 1 < TPB_TILES);
    if (have_next) {
      const float* p0 = h + ((g + 1) * TILE_ROWS + r_in0) * H_DIM + kf0;
      const float* p1 = h + ((g + 1) * TILE_ROWS + r_in1) * H_DIM + kf1;
      n0 = *(const f32x4*)p0; n1 = *(const f32x4*)(p0 + 4);
      n2 = *(const f32x4*)p1; n3 = *(const f32x4*)(p1 + 4);
    }

    // --- compute 2 row-tiles x 2 col-tiles ---
    long rowbase = g * TILE_ROWS;
#pragma unroll
    for (int rt = 0; rt < 2; ++rt) {
      f32x4 acc0 = {0.f, 0.f, 0.f, 0.f};
      f32x4 acc1 = {0.f, 0.f, 0.f, 0.f};
#pragma unroll
      for (int ks = 0; ks < 8; ++ks) {
        bf16x8 af = *(const bf16x8*)&As[buf][((rt * 8 + ks) * 64 + lane) << 3];
        acc0 = __builtin_amdgcn_mfma_f32_16x16x32_bf16(af, bfrag0[ks], acc0, 0, 0, 0);
        acc1 = __builtin_amdgcn_mfma_f32_16x16x32_bf16(af, bfrag1[ks], acc1, 0, 0, 0);
      }
      long rb = rowbase + rt * 16 + ((lane >> 4) << 2);
#pragma unroll
      for (int r = 0; r < 4; ++r) {
        int bb = batch[rb + r];
        const float* pr = pooled + bb * H_DIM;
        float* orow = out + (rb + r) * H_DIM;
        orow[o0] = acc0[r] + pr[o0];
        orow[o1] = acc1[r] + pr[o1];
      }
    }

    // --- write next tile into other buffer, then barrier ---
    if (have_next) {
      *(bf16x8*)&As[buf ^ 1][ldso0] = pack8(n0, n1);
      *(bf16x8*)&As[buf ^ 1][ldso1] = pack8(n2, n3);
    }
    __syncthreads();
  }
}

// ---------------------------------------------------------------------------
extern "C" void kernel_launch(void* const* d_in, const int* in_sizes, int n_in,
                              void* d_out, int out_size, void* d_ws, size_t ws_size,
                              hipStream_t stream) {
  const float* h   = (const float*)d_in[0];
  const float* rf  = (const float*)d_in[1];
  const int*   bat = (const int*)d_in[2];
  const float* Wp  = (const float*)d_in[3];
  const float* bp  = (const float*)d_in[4];
  const float* Wl  = (const float*)d_in[5];
  const float* bl  = (const float*)d_in[6];
  float* out = (float*)d_out;

  float* pooled = (float*)d_ws;                          // 64 KiB
  short* Bbf    = (short*)((char*)d_ws + 64 * 1024);     // 128 KiB

  prep_kernel<<<B_SZ + 16, 1024, 0, stream>>>(rf, Wp, bp, Wl, bl, pooled, Bbf);
  gemm_kernel<<<NBLOCKS, 512, 0, stream>>>(h, Bbf, pooled, bat, out);
}